// Round 8
// baseline (156.016 us; speedup 1.0000x reference)
//
#include <hip/hip_runtime.h>
#include <stdint.h>

#define B_ 16
#define N_ 25200
#define NC_ 80
#define TOPK 2048
#define MAXDET 300
#define CONF_T 0.25f
#define IOU_T 0.45f
#define MAX_WH_ 4096.0f
#define NBINS 4096
#define CAP 4096
#define CLS_CAP 256    // max candidates per class (data max ~45; 5x margin)

// ---------------- K0: zero hist1 + keepmask ----------------
__global__ __launch_bounds__(256) void k_zero(uint4* __restrict__ p, int n16) {
  int i = blockIdx.x * 256 + threadIdx.x;
  if (i < n16) p[i] = make_uint4(0u, 0u, 0u, 0u);
}

// ---------------- K1: per-anchor score/class + level-1 histogram ----------------
// 256 threads <-> 256 anchors per block, 4 chunks of 64 anchors staged in LDS.
// 4 lanes/anchor, 20 classes each, shfl_xor merge with first-max tie rule.
// hist1 built via LDS pre-aggregation (scores concentrate in ~30 hot bins).
__global__ __launch_bounds__(256) void k_score(const float* __restrict__ pred,
                                               uint32_t* __restrict__ keys,
                                               uint32_t* __restrict__ cls,
                                               uint32_t* __restrict__ hist1) {
  __shared__ float sh[64 * 85];
  __shared__ uint32_t lh[NBINS];
  const int tid = threadIdx.x;
  const int a = tid >> 2, ch = tid & 3;
  const int base_gid = blockIdx.x * 256;
  const int blk_b = base_gid / N_;
  const bool one_batch = (blk_b == (base_gid + 255) / N_);
  if (one_batch)
    for (int i = tid; i < NBINS; i += 256) lh[i] = 0;
  for (int chunk = 0; chunk < 4; ++chunk) {
    const float4* src =
        (const float4*)(pred + ((size_t)base_gid + chunk * 64) * 85);
    __syncthreads();  // prev chunk compute done (and lh zeroing visible)
    for (int i = tid; i < 64 * 85 / 4; i += 256) ((float4*)sh)[i] = src[i];
    __syncthreads();
    const int gid = base_gid + chunk * 64 + a;
    const float* row = sh + a * 85;
    const float obj = row[4];
    float best = -1.0f;
    int bj = 0;
#pragma unroll
    for (int i = 0; i < 20; ++i) {
      float v = row[5 + ch * 20 + i] * obj;  // plain mul, matches ref
      if (v > best) { best = v; bj = ch * 20 + i; }  // strict >: first max
    }
#pragma unroll
    for (int d = 1; d < 4; d <<= 1) {
      float vo = __shfl_xor(best, d, 64);
      int jo = __shfl_xor(bj, d, 64);
      if (vo > best || (vo == best && jo < bj)) { best = vo; bj = jo; }
    }
    if (ch == 0) {
      bool valid = (obj > CONF_T) && (best > CONF_T);
      float score = valid ? best : 0.0f;
      uint32_t key = __float_as_uint(score);  // score>=0: order-isomorphic
      keys[gid] = key;
      cls[gid] = (uint32_t)bj;
      if (score > CONF_T) {
        if (one_batch) atomicAdd(&lh[key >> 19], 1u);
        else atomicAdd(&hist1[(size_t)(gid / N_) * NBINS + (key >> 19)], 1u);
      }
    }
  }
  if (one_batch) {
    __syncthreads();
    for (int i = tid; i < NBINS; i += 256) {
      uint32_t cn = lh[i];
      if (cn) atomicAdd(&hist1[(size_t)blk_b * NBINS + i], cn);
    }
  }
}

// ---------------- K2: fused exact top-2048 (one block/batch) ----------------
// thresh1 -> hist2 -> thresh2 -> ballot-compact -> bitonic sort -> write+gather.
// Selection predicate & 64-bit sort keys identical to the verified chain.
__global__ __launch_bounds__(1024) void k_topk(const float* __restrict__ pred,
                                               const uint32_t* __restrict__ keys,
                                               const uint32_t* __restrict__ cls,
                                               const uint32_t* __restrict__ hist1,
                                               float* __restrict__ topk_score,
                                               float4* __restrict__ box4,
                                               float* __restrict__ clsf) {
  __shared__ uint32_t hist[NBINS];
  __shared__ uint32_t sums[1024];
  __shared__ unsigned long long cand[CAP];
  __shared__ uint32_t s_b1, s_need2, s_b2, s_cnt;
  const int b = blockIdx.x;
  const int tid = threadIdx.x;
  const int lane = tid & 63;

  // ---- Phase A: level-1 threshold from global hist1 ----
  {
    uint4 hv = ((const uint4*)(hist1 + (size_t)b * NBINS))[tid];
    uint32_t v[4] = {hv.x, hv.y, hv.z, hv.w};
    sums[tid] = v[0] + v[1] + v[2] + v[3];
    for (int d = 1; d < 1024; d <<= 1) {
      __syncthreads();
      uint32_t y = (tid + d < 1024) ? sums[tid + d] : 0;
      __syncthreads();
      sums[tid] += y;
    }
    __syncthreads();
    const uint32_t need = TOPK;
    uint32_t above = (tid + 1 < 1024) ? sums[tid + 1] : 0;
    if (above < need && sums[tid] >= need) {
      uint32_t cum = above;
      for (int i = 3; i >= 0; --i) {
        if (cum + v[i] >= need) { s_b1 = (uint32_t)(tid * 4 + i); s_need2 = need - cum; break; }
        cum += v[i];
      }
    }
    if (tid == 0 && sums[0] < need) { s_b1 = 2000u; s_need2 = 0xFFFFFFFFu; }
  }
  __syncthreads();
  const uint32_t b1 = s_b1, need2 = s_need2;

  // ---- Phase B: level-2 LDS histogram within boundary bin ----
  for (int i = tid; i < NBINS; i += 1024) hist[i] = 0;
  __syncthreads();
  const uint32_t* kb = keys + (size_t)b * N_;
  for (int n = tid; n < N_; n += 1024) {
    uint32_t k = kb[n];
    if ((k >> 19) == b1) atomicAdd(&hist[(k >> 7) & 4095u], 1u);
  }
  __syncthreads();

  // ---- Phase C: level-2 threshold ----
  {
    uint32_t v[4];
#pragma unroll
    for (int i = 0; i < 4; ++i) v[i] = hist[tid * 4 + i];
    sums[tid] = v[0] + v[1] + v[2] + v[3];
    for (int d = 1; d < 1024; d <<= 1) {
      __syncthreads();
      uint32_t y = (tid + d < 1024) ? sums[tid + d] : 0;
      __syncthreads();
      sums[tid] += y;
    }
    __syncthreads();
    const uint32_t need = need2;
    uint32_t above = (tid + 1 < 1024) ? sums[tid + 1] : 0;
    if (above < need && sums[tid] >= need) {
      uint32_t cum = above;
      for (int i = 3; i >= 0; --i) {
        if (cum + v[i] >= need) { s_b2 = (uint32_t)(tid * 4 + i); break; }
        cum += v[i];
      }
    }
    if (tid == 0) { s_cnt = 0; if (sums[0] < need) s_b2 = 0; }
  }
  __syncthreads();
  const uint32_t b2 = s_b2;

  // ---- Phase D: ballot-compacted candidate collection ----
  for (int it = 0; it < (N_ + 1023) / 1024; ++it) {
    int n = it * 1024 + tid;
    bool m = false;
    uint32_t k = 0;
    if (n < N_) {
      k = kb[n];
      uint32_t bin = k >> 19;
      m = (bin > b1) || (bin == b1 && ((k >> 7) & 4095u) >= b2);
    }
    unsigned long long mask = __ballot(m);
    uint32_t base = 0;
    if (lane == 0 && mask) base = atomicAdd(&s_cnt, (uint32_t)__popcll(mask));
    base = (uint32_t)__shfl((int)base, 0, 64);
    if (m) {
      uint32_t pos = base + (uint32_t)__popcll(mask & ((1ull << lane) - 1ull));
      if (pos < CAP)
        cand[pos] = ((unsigned long long)k << 32) | (uint32_t)(~(uint32_t)n);
    }
  }
  __syncthreads();
  uint32_t cnt = s_cnt < CAP ? s_cnt : CAP;
  for (int i = (int)cnt + tid; i < CAP; i += 1024) cand[i] = 0ull;
  __syncthreads();

  // ---- Phase E: bitonic sort, descending ----
  for (unsigned k = 2; k <= CAP; k <<= 1) {
    for (unsigned j = k >> 1; j > 0; j >>= 1) {
      for (unsigned i = tid; i < CAP; i += 1024) {
        unsigned ixj = i ^ j;
        if (ixj > i) {
          unsigned long long a = cand[i], d = cand[ixj];
          bool desc = ((i & k) == 0);
          if (desc ? (a < d) : (a > d)) { cand[i] = d; cand[ixj] = a; }
        }
      }
      __syncthreads();
    }
  }

  // ---- Phase F: write scores + gather boxes/class (k_prep fused) ----
  for (int r = tid; r < TOPK; r += 1024) {
    unsigned long long key = cand[r];
    uint32_t idx = ~((uint32_t)(key & 0xFFFFFFFFull));
    if (idx >= N_) idx = 0;  // pad entry (score==0, filtered downstream)
    topk_score[(size_t)b * TOPK + r] = __uint_as_float((uint32_t)(key >> 32));
    const float* p = pred + ((size_t)b * N_ + idx) * 85;
    float x = p[0], y = p[1], w = p[2], h = p[3];
    float hw = w * 0.5f, hh = h * 0.5f;  // exact (pow2 scale)
    box4[(size_t)b * TOPK + r] = make_float4(x - hw, y - hh, x + hw, y + hh);
    clsf[(size_t)b * TOPK + r] = (float)cls[(size_t)b * N_ + idx];
  }
}

// ---------------- K4: per-class greedy NMS (one wave per (batch,class)) ----------------
// Cross-class pairs have IoU exactly 0 (class offset 4096 >> box extent), so the
// reference's global rank-order greedy decomposes exactly into per-class scans.
// IoU math replicates the reference bit-for-bit INCLUDING the offset-box rounding.
__global__ __launch_bounds__(64) void k_nmscls(const float4* __restrict__ box4,
                                               const float* __restrict__ clsf,
                                               const float* __restrict__ topk_score,
                                               uint32_t* __restrict__ keepmask) {
  __shared__ float4 ob[CLS_CAP];
  __shared__ uint32_t rk[CLS_CAP];
  const int b = blockIdx.y;
  const int c = blockIdx.x;
  const int l = threadIdx.x;
  const float cf = (float)c;
  const float offv = cf * MAX_WH_;  // exact (pow2 scale)
  int n = 0;
  for (int chunk = 0; chunk < TOPK / 64; ++chunk) {
    int r = chunk * 64 + l;
    float s = topk_score[(size_t)b * TOPK + r];
    float cv = clsf[(size_t)b * TOPK + r];
    bool m = (s > CONF_T) && (cv == cf);
    unsigned long long mask = __ballot(m);
    if (m) {
      int pos = n + __popcll(mask & ((1ull << l) - 1ull));
      if (pos < CLS_CAP) {
        float4 bx = box4[(size_t)b * TOPK + r];
        ob[pos] = make_float4(__fadd_rn(bx.x, offv), __fadd_rn(bx.y, offv),
                              __fadd_rn(bx.z, offv), __fadd_rn(bx.w, offv));
        rk[pos] = (uint32_t)r;
      }
    }
    n += (int)__popcll(mask);
  }
  if (n > CLS_CAP) n = CLS_CAP;
  __syncthreads();
  float4 bj[4]; float aj[4];
#pragma unroll
  for (int t = 0; t < 4; ++t) {
    int j = l + 64 * t;
    if (j < n) {
      bj[t] = ob[j];
      aj[t] = __fmul_rn(__fsub_rn(bj[t].z, bj[t].x), __fsub_rn(bj[t].w, bj[t].y));
    }
  }
  uint32_t supp = 0, keptbits = 0;
  for (int i = 0; i < n; ++i) {
    int owner = i & 63, word = i >> 6;
    uint32_t so = (uint32_t)__shfl((int)supp, owner, 64);
    bool kept_i = !((so >> word) & 1u);
    if (l == owner && kept_i) keptbits |= 1u << word;
    if (kept_i) {
      float4 bi = ob[i];
      float a1 = __fmul_rn(__fsub_rn(bi.z, bi.x), __fsub_rn(bi.w, bi.y));
#pragma unroll
      for (int t = 0; t < 4; ++t) {
        int j = l + 64 * t;
        if (j > i && j < n && !((supp >> t) & 1u)) {
          float ltx = fmaxf(bi.x, bj[t].x), lty = fmaxf(bi.y, bj[t].y);
          float rbx = fminf(bi.z, bj[t].z), rby = fminf(bi.w, bj[t].w);
          float dx = fmaxf(__fsub_rn(rbx, ltx), 0.0f);
          float dy = fmaxf(__fsub_rn(rby, lty), 0.0f);
          float inter = __fmul_rn(dx, dy);
          float uni = __fsub_rn(__fadd_rn(a1, aj[t]), inter);
          if (inter > 0.0f && __fdiv_rn(inter, uni) > IOU_T) supp |= 1u << t;
        }
      }
    }
  }
#pragma unroll
  for (int t = 0; t < 4; ++t) {
    int j = l + 64 * t;
    if (j < n && ((keptbits >> t) & 1u)) {
      uint32_t r = rk[j];
      atomicOr(&keepmask[b * 64 + (r >> 5)], 1u << (r & 31));
    }
  }
}

// ---------------- K6: emit up to 300 rows + count ----------------
__global__ __launch_bounds__(64) void k_out(const uint32_t* __restrict__ keepmask,
                                            const float4* __restrict__ box4,
                                            const float* __restrict__ topk_score,
                                            const float* __restrict__ clsf,
                                            float* __restrict__ out,
                                            float* __restrict__ out_counts) {
  const int b = blockIdx.x;
  const int l = threadIdx.x;
  float* ob = out + (size_t)b * MAXDET * 6;
  for (int t = l; t < MAXDET * 6; t += 64) ob[t] = 0.0f;
  __syncthreads();
  uint32_t w = keepmask[b * 64 + l];
  int pc = __popc(w);
  int pre = pc;
  for (int off = 1; off < 64; off <<= 1) {
    int v = __shfl_up(pre, off, 64);
    if (l >= off) pre += v;
  }
  if (l == 63) out_counts[b] = (float)pre;  // total kept
  int r = pre - pc;  // exclusive prefix of kept counts
  for (int jj = 0; jj < 32; ++jj) {
    if ((w >> jj) & 1u) {
      if (r < MAXDET) {
        int k = l * 32 + jj;
        float4 bx = box4[(size_t)b * TOPK + k];
        float sc = topk_score[(size_t)b * TOPK + k];
        float cf = clsf[(size_t)b * TOPK + k];
        float* row = ob + (size_t)r * 6;
        row[0] = bx.x; row[1] = bx.y; row[2] = bx.z; row[3] = bx.w;
        row[4] = sc;   row[5] = cf;
      }
      ++r;
    }
  }
}

extern "C" void kernel_launch(void* const* d_in, const int* in_sizes, int n_in,
                              void* d_out, int out_size, void* d_ws, size_t ws_size,
                              hipStream_t stream) {
  const float* pred = (const float*)d_in[0];
  float* out = (float*)d_out;

  char* ws = (char*)d_ws;
  size_t off = 0;
  // --- zeroed-each-launch region (contiguous): hist1, keepmask ---
  uint32_t* hist1 = (uint32_t*)(ws + off); off += (size_t)B_ * NBINS * 4;        // 256 KB
  uint32_t* keepmask = (uint32_t*)(ws + off); off += (size_t)B_ * 64 * 4;        // 4 KB
  size_t zero_bytes = off;
  // --- rest ---
  uint32_t* keys = (uint32_t*)(ws + off); off += (size_t)B_ * N_ * 4;            // 1.6 MB
  uint32_t* cls = (uint32_t*)(ws + off);  off += (size_t)B_ * N_ * 4;            // 1.6 MB
  float* topk_score = (float*)(ws + off);  off += (size_t)B_ * TOPK * 4;         // 128 KB
  float4* box4 = (float4*)(ws + off);      off += (size_t)B_ * TOPK * 16;        // 512 KB
  float* clsf = (float*)(ws + off);        off += (size_t)B_ * TOPK * 4;         // 128 KB

  (void)in_sizes; (void)n_in; (void)out_size; (void)ws_size;

  int n16 = (int)(zero_bytes / 16);
  k_zero<<<(n16 + 255) / 256, 256, 0, stream>>>((uint4*)ws, n16);
  int grid_n = (B_ * N_ + 255) / 256;
  k_score<<<grid_n, 256, 0, stream>>>(pred, keys, cls, hist1);
  k_topk<<<B_, 1024, 0, stream>>>(pred, keys, cls, hist1, topk_score, box4, clsf);
  dim3 ngrid(NC_, B_);
  k_nmscls<<<ngrid, 64, 0, stream>>>(box4, clsf, topk_score, keepmask);
  k_out<<<B_, 64, 0, stream>>>(keepmask, box4, topk_score, clsf, out,
                               out + (size_t)B_ * MAXDET * 6);
}

// Round 9
// 129.411 us; speedup vs baseline: 1.2056x; 1.2056x over previous
//
#include <hip/hip_runtime.h>
#include <stdint.h>

#define B_ 16
#define N_ 25200
#define NC_ 80
#define TOPK 2048
#define MAXDET 300
#define CONF_T 0.25f
#define IOU_T 0.45f
#define MAX_WH_ 4096.0f
#define NBINS 4096
#define CAP 6144       // superset bound after level-1 threshold (~2.6k realistic)
#define CLS_CAP 256    // max candidates per class (data max ~45; 5x margin)
#define CNT_STRIDE 32  // pad counters to 128B
#define RANK_T 128     // threads per rank block

// ---------------- K0: zero hist1 + cnt + keepmask + topk_score ----------------
__global__ __launch_bounds__(256) void k_zero(uint4* __restrict__ p, int n16) {
  int i = blockIdx.x * 256 + threadIdx.x;
  if (i < n16) p[i] = make_uint4(0u, 0u, 0u, 0u);
}

// ---------------- K1: per-anchor score/class + level-1 histogram ----------------
// 256 threads <-> 256 anchors per block, 4 chunks of 64 anchors staged in LDS.
// 4 lanes/anchor, 20 classes each, shfl_xor merge with first-max tie rule.
// hist1 via LDS pre-aggregation (scores concentrate in ~30 hot bins).
__global__ __launch_bounds__(256) void k_score(const float* __restrict__ pred,
                                               uint32_t* __restrict__ keys,
                                               uint32_t* __restrict__ cls,
                                               uint32_t* __restrict__ hist1) {
  __shared__ float sh[64 * 85];
  __shared__ uint32_t lh[NBINS];
  const int tid = threadIdx.x;
  const int a = tid >> 2, ch = tid & 3;
  const int base_gid = blockIdx.x * 256;
  const int blk_b = base_gid / N_;
  const bool one_batch = (blk_b == (base_gid + 255) / N_);
  if (one_batch)
    for (int i = tid; i < NBINS; i += 256) lh[i] = 0;
  for (int chunk = 0; chunk < 4; ++chunk) {
    const float4* src =
        (const float4*)(pred + ((size_t)base_gid + chunk * 64) * 85);
    __syncthreads();  // prev chunk compute done (and lh zeroing visible)
    for (int i = tid; i < 64 * 85 / 4; i += 256) ((float4*)sh)[i] = src[i];
    __syncthreads();
    const int gid = base_gid + chunk * 64 + a;
    const float* row = sh + a * 85;
    const float obj = row[4];
    float best = -1.0f;
    int bj = 0;
#pragma unroll
    for (int i = 0; i < 20; ++i) {
      float v = row[5 + ch * 20 + i] * obj;  // plain mul, matches ref
      if (v > best) { best = v; bj = ch * 20 + i; }  // strict >: first max
    }
#pragma unroll
    for (int d = 1; d < 4; d <<= 1) {
      float vo = __shfl_xor(best, d, 64);
      int jo = __shfl_xor(bj, d, 64);
      if (vo > best || (vo == best && jo < bj)) { best = vo; bj = jo; }
    }
    if (ch == 0) {
      bool valid = (obj > CONF_T) && (best > CONF_T);
      float score = valid ? best : 0.0f;
      uint32_t key = __float_as_uint(score);  // score>=0: order-isomorphic
      keys[gid] = key;
      cls[gid] = (uint32_t)bj;
      if (score > CONF_T) {
        if (one_batch) atomicAdd(&lh[key >> 19], 1u);
        else atomicAdd(&hist1[(size_t)(gid / N_) * NBINS + (key >> 19)], 1u);
      }
    }
  }
  if (one_batch) {
    __syncthreads();
    for (int i = tid; i < NBINS; i += 256) {
      uint32_t cn = lh[i];
      if (cn) atomicAdd(&hist1[(size_t)blk_b * NBINS + i], cn);
    }
  }
}

// ---------------- K2: level-1 threshold (one block/batch) ----------------
// b1 = largest bin with suffix_count >= TOPK. Selecting bins >= b1 gives an
// exact superset of the true top-2048 (resolved exactly by k_rank).
__global__ __launch_bounds__(256) void k_thresh(const uint32_t* __restrict__ hist,
                                                uint32_t* __restrict__ b_out) {
  __shared__ uint32_t sums[256];
  const int b = blockIdx.x;
  const int t = threadIdx.x;
  const uint32_t* h = hist + (size_t)b * NBINS + t * 16;
  uint32_t v[16];
  uint32_t loc = 0;
#pragma unroll
  for (int i = 0; i < 16; ++i) { v[i] = h[i]; loc += v[i]; }
  sums[t] = loc;
  for (int d = 1; d < 256; d <<= 1) {
    __syncthreads();
    uint32_t y = (t + d < 256) ? sums[t + d] : 0;
    __syncthreads();
    sums[t] += y;
  }
  __syncthreads();
  const uint32_t need = TOPK;
  uint32_t above = (t + 1 < 256) ? sums[t + 1] : 0;
  if (above < need && sums[t] >= need) {  // exactly one crossing thread
    uint32_t cum = above;
    for (int i = 15; i >= 0; --i) {
      if (cum + v[i] >= need) { b_out[b] = (uint32_t)(t * 16 + i); break; }
      cum += v[i];
    }
  }
  if (t == 0 && sums[0] < need) b_out[b] = 1;  // <2048 valid: take all valid
}

// ---------------- K3: compact candidates (block-aggregated atomics) ----------------
__global__ __launch_bounds__(256) void k_compact(const uint32_t* __restrict__ keys,
                                                 const uint32_t* __restrict__ b1v,
                                                 uint32_t* __restrict__ cnt,
                                                 unsigned long long* __restrict__ cand) {
  __shared__ uint32_t s_cnt, s_base;
  const int b = blockIdx.y;
  const int n = blockIdx.x * 256 + threadIdx.x;
  if (threadIdx.x == 0) s_cnt = 0;
  __syncthreads();
  uint32_t k = 0, loc = 0xFFFFFFFFu;
  if (n < N_) {
    k = keys[(size_t)b * N_ + n];
    if ((k >> 19) >= b1v[b]) loc = atomicAdd(&s_cnt, 1u);  // LDS atomic
  }
  __syncthreads();
  if (threadIdx.x == 0) s_base = atomicAdd(&cnt[b * CNT_STRIDE], s_cnt);
  __syncthreads();
  if (loc != 0xFFFFFFFFu) {
    uint32_t p = s_base + loc;
    if (p < CAP)
      cand[(size_t)b * CAP + p] = ((unsigned long long)k << 32) | (uint32_t)(~(uint32_t)n);
  }
}

// ---------------- K4: exact rank by counting + gather (grid-parallel) ----------------
// Keys are unique (low bits = ~idx) so rank_i = #{j: key_j > key_i} is exact and
// equals the position lax.top_k would assign. rank<TOPK -> emit at slot rank.
__global__ __launch_bounds__(RANK_T) void k_rank(const float* __restrict__ pred,
                                                 const uint32_t* __restrict__ cls,
                                                 const unsigned long long* __restrict__ cand,
                                                 const uint32_t* __restrict__ cnt,
                                                 float* __restrict__ topk_score,
                                                 float4* __restrict__ box4,
                                                 float* __restrict__ clsf) {
  __shared__ unsigned long long sh[CAP];
  const int b = blockIdx.y;
  int n = (int)cnt[b * CNT_STRIDE];
  if (n > CAP) n = CAP;
  const int own = blockIdx.x * RANK_T + threadIdx.x;
  if (blockIdx.x * RANK_T >= n) return;  // whole block idle (uniform exit)
  const unsigned long long* cb = cand + (size_t)b * CAP;
  for (int i = threadIdx.x; i < n; i += RANK_T) sh[i] = cb[i];
  __syncthreads();
  if (own >= n) return;
  const unsigned long long ki = sh[own];
  uint32_t rank = 0;
  int j = 0;
  for (; j + 8 <= n; j += 8) {
#pragma unroll
    for (int u = 0; u < 8; ++u) rank += (sh[j + u] > ki) ? 1u : 0u;
  }
  for (; j < n; ++j) rank += (sh[j] > ki) ? 1u : 0u;
  if (rank < TOPK) {
    uint32_t idx = ~((uint32_t)(ki & 0xFFFFFFFFull));
    topk_score[(size_t)b * TOPK + rank] = __uint_as_float((uint32_t)(ki >> 32));
    const float* p = pred + ((size_t)b * N_ + idx) * 85;
    float x = p[0], y = p[1], w = p[2], h = p[3];
    float hw = w * 0.5f, hh = h * 0.5f;  // exact (pow2 scale)
    box4[(size_t)b * TOPK + rank] = make_float4(x - hw, y - hh, x + hw, y + hh);
    clsf[(size_t)b * TOPK + rank] = (float)cls[(size_t)b * N_ + idx];
  }
}

// ---------------- K5: per-class greedy NMS (one wave per (batch,class)) ----------------
// Cross-class IoU is exactly 0 (class offset 4096 >> box extent), so the global
// rank-order greedy decomposes exactly into per-class scans. IoU math replicates
// the reference bit-for-bit INCLUDING offset-box rounding.
__global__ __launch_bounds__(64) void k_nmscls(const float4* __restrict__ box4,
                                               const float* __restrict__ clsf,
                                               const float* __restrict__ topk_score,
                                               uint32_t* __restrict__ keepmask) {
  __shared__ float4 ob[CLS_CAP];
  __shared__ uint32_t rk[CLS_CAP];
  const int b = blockIdx.y;
  const int c = blockIdx.x;
  const int l = threadIdx.x;
  const float cf = (float)c;
  const float offv = cf * MAX_WH_;  // exact (pow2 scale)
  int n = 0;
  for (int chunk = 0; chunk < TOPK / 64; ++chunk) {
    int r = chunk * 64 + l;
    float s = topk_score[(size_t)b * TOPK + r];
    float cv = clsf[(size_t)b * TOPK + r];
    bool m = (s > CONF_T) && (cv == cf);
    unsigned long long mask = __ballot(m);
    if (m) {
      int pos = n + __popcll(mask & ((1ull << l) - 1ull));
      if (pos < CLS_CAP) {
        float4 bx = box4[(size_t)b * TOPK + r];
        ob[pos] = make_float4(__fadd_rn(bx.x, offv), __fadd_rn(bx.y, offv),
                              __fadd_rn(bx.z, offv), __fadd_rn(bx.w, offv));
        rk[pos] = (uint32_t)r;
      }
    }
    n += (int)__popcll(mask);
  }
  if (n > CLS_CAP) n = CLS_CAP;
  __syncthreads();
  float4 bj[4]; float aj[4];
#pragma unroll
  for (int t = 0; t < 4; ++t) {
    int j = l + 64 * t;
    if (j < n) {
      bj[t] = ob[j];
      aj[t] = __fmul_rn(__fsub_rn(bj[t].z, bj[t].x), __fsub_rn(bj[t].w, bj[t].y));
    }
  }
  uint32_t supp = 0, keptbits = 0;
  for (int i = 0; i < n; ++i) {
    int owner = i & 63, word = i >> 6;
    uint32_t so = (uint32_t)__shfl((int)supp, owner, 64);
    bool kept_i = !((so >> word) & 1u);
    if (l == owner && kept_i) keptbits |= 1u << word;
    if (kept_i) {
      float4 bi = ob[i];
      float a1 = __fmul_rn(__fsub_rn(bi.z, bi.x), __fsub_rn(bi.w, bi.y));
#pragma unroll
      for (int t = 0; t < 4; ++t) {
        int j = l + 64 * t;
        if (j > i && j < n && !((supp >> t) & 1u)) {
          float ltx = fmaxf(bi.x, bj[t].x), lty = fmaxf(bi.y, bj[t].y);
          float rbx = fminf(bi.z, bj[t].z), rby = fminf(bi.w, bj[t].w);
          float dx = fmaxf(__fsub_rn(rbx, ltx), 0.0f);
          float dy = fmaxf(__fsub_rn(rby, lty), 0.0f);
          float inter = __fmul_rn(dx, dy);
          float uni = __fsub_rn(__fadd_rn(a1, aj[t]), inter);
          if (inter > 0.0f && __fdiv_rn(inter, uni) > IOU_T) supp |= 1u << t;
        }
      }
    }
  }
#pragma unroll
  for (int t = 0; t < 4; ++t) {
    int j = l + 64 * t;
    if (j < n && ((keptbits >> t) & 1u)) {
      uint32_t r = rk[j];
      atomicOr(&keepmask[b * 64 + (r >> 5)], 1u << (r & 31));
    }
  }
}

// ---------------- K6: emit up to 300 rows + count ----------------
__global__ __launch_bounds__(64) void k_out(const uint32_t* __restrict__ keepmask,
                                            const float4* __restrict__ box4,
                                            const float* __restrict__ topk_score,
                                            const float* __restrict__ clsf,
                                            float* __restrict__ out,
                                            float* __restrict__ out_counts) {
  const int b = blockIdx.x;
  const int l = threadIdx.x;
  float* ob = out + (size_t)b * MAXDET * 6;
  for (int t = l; t < MAXDET * 6; t += 64) ob[t] = 0.0f;
  __syncthreads();
  uint32_t w = keepmask[b * 64 + l];
  int pc = __popc(w);
  int pre = pc;
  for (int off = 1; off < 64; off <<= 1) {
    int v = __shfl_up(pre, off, 64);
    if (l >= off) pre += v;
  }
  if (l == 63) out_counts[b] = (float)pre;  // total kept
  int r = pre - pc;  // exclusive prefix of kept counts
  for (int jj = 0; jj < 32; ++jj) {
    if ((w >> jj) & 1u) {
      if (r < MAXDET) {
        int k = l * 32 + jj;
        float4 bx = box4[(size_t)b * TOPK + k];
        float sc = topk_score[(size_t)b * TOPK + k];
        float cf = clsf[(size_t)b * TOPK + k];
        float* row = ob + (size_t)r * 6;
        row[0] = bx.x; row[1] = bx.y; row[2] = bx.z; row[3] = bx.w;
        row[4] = sc;   row[5] = cf;
      }
      ++r;
    }
  }
}

extern "C" void kernel_launch(void* const* d_in, const int* in_sizes, int n_in,
                              void* d_out, int out_size, void* d_ws, size_t ws_size,
                              hipStream_t stream) {
  const float* pred = (const float*)d_in[0];
  float* out = (float*)d_out;

  char* ws = (char*)d_ws;
  size_t off = 0;
  // --- zeroed-each-launch region (contiguous) ---
  uint32_t* hist1 = (uint32_t*)(ws + off); off += (size_t)B_ * NBINS * 4;        // 256 KB
  uint32_t* keepmask = (uint32_t*)(ws + off); off += (size_t)B_ * 64 * 4;        // 4 KB
  uint32_t* cnt   = (uint32_t*)(ws + off); off += (size_t)B_ * CNT_STRIDE * 4;   // 2 KB
  float* topk_score = (float*)(ws + off);  off += (size_t)B_ * TOPK * 4;         // 128 KB
  size_t zero_bytes = off;
  // --- rest ---
  uint32_t* b1v   = (uint32_t*)(ws + off); off += 64;
  uint32_t* keys = (uint32_t*)(ws + off); off += (size_t)B_ * N_ * 4;            // 1.6 MB
  uint32_t* cls = (uint32_t*)(ws + off);  off += (size_t)B_ * N_ * 4;            // 1.6 MB
  unsigned long long* cand = (unsigned long long*)(ws + off); off += (size_t)B_ * CAP * 8;  // 786 KB
  float4* box4 = (float4*)(ws + off);      off += (size_t)B_ * TOPK * 16;        // 512 KB
  float* clsf = (float*)(ws + off);        off += (size_t)B_ * TOPK * 4;         // 128 KB

  (void)in_sizes; (void)n_in; (void)out_size; (void)ws_size;

  int n16 = (int)(zero_bytes / 16);
  k_zero<<<(n16 + 255) / 256, 256, 0, stream>>>((uint4*)ws, n16);
  int grid_n = (B_ * N_ + 255) / 256;
  k_score<<<grid_n, 256, 0, stream>>>(pred, keys, cls, hist1);
  k_thresh<<<B_, 256, 0, stream>>>(hist1, b1v);
  dim3 cgrid((N_ + 255) / 256, B_);
  k_compact<<<cgrid, 256, 0, stream>>>(keys, b1v, cnt, cand);
  dim3 rgrid(CAP / RANK_T, B_);
  k_rank<<<rgrid, RANK_T, 0, stream>>>(pred, cls, cand, cnt, topk_score, box4, clsf);
  dim3 ngrid(NC_, B_);
  k_nmscls<<<ngrid, 64, 0, stream>>>(box4, clsf, topk_score, keepmask);
  k_out<<<B_, 64, 0, stream>>>(keepmask, box4, topk_score, clsf, out,
                               out + (size_t)B_ * MAXDET * 6);
}